// Round 1
// baseline (195.197 us; speedup 1.0000x reference)
//
#include <hip/hip_runtime.h>

// Boundary_binaryLoss: 15x15 binary morphology boundary mask + masked NLL mean.
// B=32, C=2, H=480, W=864. logits [B,C,H,W] f32, labels [B,H,W] i32 in {0,1,255}.
//
// valid(b,h,w) = (label != 255) && (clipped 15x15 window contains a pixel with
//   np_label==0 (label 0 or 255) AND a pixel with np_label==255 (label 1))
// loss = -sum(valid ? logits[b,label,h,w] : 0) / max(#valid, 1)
//
// R1: same-line device atomics serialized (180us) -> per-block double2 partials.
// R2: tried register-prefetching logits past both barriers. FAILED silently:
//     profile shows VGPR_Count=24, which cannot hold 4x int4 + 4x float4 in
//     flight -> compiler sank the loads back into phase 3 (legal: read-only
//     memory moves across __syncthreads). Block tail re-exposed ~900cy HBM
//     latency; VALUBusy 27%, HBM 24%, occupancy 63% = latency-bound.
// R3: logits tile (16 KB) staged via __builtin_amdgcn_global_load_lds — async
//     DMA with ZERO VGPR footprint, so nothing can be sunk. Issued right after
//     the label loads; the first __syncthreads' mandatory vmcnt(0) drain lands
//     after label-load + flag-pack, hiding the logits latency under work that
//     must happen anyway. Phase 3 is now pure LDS. Also dropped sraw: center
//     ignore/label ride in sflag bits (bit2=ignore, bit1=label1), halving
//     phase-1 LDS writes. LDS/block = 23.0 KB -> 7 blocks/CU (28 waves).

namespace {
constexpr int B_ = 32;
constexpr int H_ = 480;
constexpr int W_ = 864;
constexpr int TW = 64;
constexpr int TH = 32;
constexpr int R_ = 7;
constexpr int LH = TH + 2 * R_;   // 46 halo rows
constexpr int WC = 20;            // 80 halo labels per row, packed as byte-dwords
constexpr int HC = TW / 4;        // 16 output dwords per row
constexpr int GX = (W_ + TW - 1) / TW;  // 14
constexpr int GY = H_ / TH;             // 15
constexpr int NBLK = GX * GY * B_;      // 6720
} // namespace

typedef const __attribute__((address_space(1))) void GVOID;
typedef __attribute__((address_space(3))) void LVOID;

__device__ __forceinline__ unsigned fold4(unsigned x) {
  x |= x >> 16;
  x |= x >> 8;
  return x & 0xFFu;
}

__device__ __forceinline__ unsigned flag_of(int v) {
  // bit0: np_label==0 (v==0 or v==255); bit1: np_label==255 (v==1);
  // bit2: center-ignore (v==255).
  return (v == 0) ? 1u : (v == 1) ? 2u : (v == 255) ? 5u : 0u;
}

extern "C" __global__ __launch_bounds__(256, 8)
void boundary_loss_main(const float* __restrict__ logits,
                        const int* __restrict__ labels,
                        double2* __restrict__ partials)
{
  __shared__ float slg[2][TH][TW];    // 16 KB DMA-staged logits tile
  __shared__ unsigned sflag[LH][WC];  // per-byte window flags (+center bits)
  __shared__ unsigned hfl[LH][HC];    // horizontal 15-OR result
  __shared__ double red_s[4];
  __shared__ unsigned red_c[4];

  const int tid = threadIdx.x;
  const int tile_w = blockIdx.x * TW;
  const int tile_h = blockIdx.y * TH;
  const int b = blockIdx.z;

  const int* __restrict__ lab = labels + (size_t)b * H_ * W_;
  const float* __restrict__ lg0 = logits + (size_t)b * 2 * H_ * W_;

  // ---- label halo loads into registers (issued FIRST so phase-1's waitcnt
  //      is vmcnt(4), leaving the logits DMA in flight) ----
  int4 lv[4];
#pragma unroll
  for (int u = 0; u < 4; ++u) {
    const int it = tid + 256 * u;
    const int r = it / WC;
    const int wcc = it - r * WC;
    const int gh = tile_h - R_ + r;
    const int gw = tile_w - 8 + wcc * 4;
    lv[u] = make_int4(200, 200, 200, 200);  // OOB: flag 0
    if (it < LH * WC && gh >= 0 && gh < H_ && gw >= 0 && gw < W_)
      lv[u] = *(const int4*)(lab + (size_t)gh * W_ + gw);
  }

  // ---- async logits -> LDS: 16 chunks of 1 KB (4 rows x 64 floats), 4 per
  //      wave. LDS dest is wave-uniform base + lane*16; global src is
  //      per-lane. Zero VGPR data footprint. ----
  {
    const int lane = tid & 63;
    const int wave = tid >> 6;
    const int lr = lane >> 4;        // row within chunk, 0..3
    int gcol = tile_w + (lane & 15) * 4;
    if (gcol > W_ - 4) gcol = W_ - 4;  // clamp last tile; junk cols never read
#pragma unroll
    for (int i = 0; i < 4; ++i) {
      const int chunk = wave * 4 + i;       // 0..15
      const int ch = chunk >> 3;            // channel
      const int rb = (chunk & 7) * 4;       // row base within tile
      const float* src = lg0 + (size_t)ch * H_ * W_ +
                         (size_t)(tile_h + rb + lr) * W_ + gcol;
      __builtin_amdgcn_global_load_lds((GVOID*)src, (LVOID*)&slg[ch][rb][0],
                                       16, 0, 0);
    }
  }

  // ================= phase 1: pack label flags -> LDS =================
#pragma unroll
  for (int u = 0; u < 4; ++u) {
    const int it = tid + 256 * u;
    if (it < LH * WC) {
      const int r = it / WC;
      const int wcc = it - r * WC;
      const int4 v = lv[u];
      const unsigned flg = flag_of(v.x) | (flag_of(v.y) << 8) |
                           (flag_of(v.z) << 16) | (flag_of(v.w) << 24);
      sflag[r][wcc] = flg;
    }
  }
  __syncthreads();  // also drains vmcnt(0): slg is complete past this point

  // ================= phase 2: horizontal 15-wide OR =================
  // output col c (tile coords, c=wc*4) windows cover halo bytes in dwords
  // wc..wc+4 of the 80-byte halo row. bit2 rides along; masked in phase 3.
  for (int it = tid; it < LH * HC; it += 256) {
    const int r = it >> 4;
    const int wc = it & 15;
    const unsigned w0 = sflag[r][wc];
    const unsigned w1 = sflag[r][wc + 1];
    const unsigned w2 = sflag[r][wc + 2];
    const unsigned w3 = sflag[r][wc + 3];
    const unsigned w4 = sflag[r][wc + 4];
    const unsigned core = fold4(w1 | w2 | w3);
    const unsigned o0 = core | fold4(w0 >> 8);                    // c+1..c+15
    const unsigned o1 = core | fold4(w0 >> 16) | (w4 & 0xFFu);    // c+2..c+16
    const unsigned o2 = core | (w0 >> 24) | fold4(w4 & 0xFFFFu);  // c+3..c+17
    const unsigned o3 = core | fold4(w4 & 0xFFFFFFu);             // c+4..c+18
    hfl[r][wc] = o0 | (o1 << 8) | (o2 << 16) | (o3 << 24);
  }
  __syncthreads();

  // ===== phase 3: vertical 15-OR + select staged logits (all LDS) =====
  double lsum = 0.0;
  unsigned lcnt = 0;
  const int r0 = tid >> 4;   // 0..15
  const int wcp = tid & 15;
  if (tile_w + wcp * 4 < W_) {  // last tile covers only cols 832..863
    unsigned accA = 0, accB = 0;
#pragma unroll
    for (int k = 0; k < 15; ++k) {
      accA |= hfl[r0 + k][wcp];
      accB |= hfl[r0 + 16 + k][wcp];
    }
    const unsigned cfA = sflag[r0 + R_][wcp + 2];       // center flag bytes
    const unsigned cfB = sflag[r0 + 16 + R_][wcp + 2];
    const float4 a0 = *(const float4*)&slg[0][r0][wcp * 4];
    const float4 a1 = *(const float4*)&slg[1][r0][wcp * 4];
    const float4 b0 = *(const float4*)&slg[0][r0 + 16][wcp * 4];
    const float4 b1 = *(const float4*)&slg[1][r0 + 16][wcp * 4];
    const float cA0[4] = {a0.x, a0.y, a0.z, a0.w};
    const float cA1[4] = {a1.x, a1.y, a1.z, a1.w};
    const float cB0[4] = {b0.x, b0.y, b0.z, b0.w};
    const float cB1[4] = {b1.x, b1.y, b1.z, b1.w};
#pragma unroll
    for (int j = 0; j < 4; ++j) {
      const unsigned fA = (accA >> (8 * j)) & 0xFFu;
      const unsigned cA = (cfA >> (8 * j)) & 0xFFu;
      const bool okA = ((fA & 3u) == 3u) && !(cA & 4u);
      lsum += okA ? (double)((cA & 2u) ? cA1[j] : cA0[j]) : 0.0;
      lcnt += okA;
      const unsigned fB = (accB >> (8 * j)) & 0xFFu;
      const unsigned cB = (cfB >> (8 * j)) & 0xFFu;
      const bool okB = ((fB & 3u) == 3u) && !(cB & 4u);
      lsum += okB ? (double)((cB & 2u) ? cB1[j] : cB0[j]) : 0.0;
      lcnt += okB;
    }
  }

  // ---- block reduction -> ONE double2 store per block (no atomics) ----
#pragma unroll
  for (int off = 32; off > 0; off >>= 1) {
    lsum += __shfl_down(lsum, off, 64);
    lcnt += __shfl_down(lcnt, off, 64);
  }
  const int wave = tid >> 6;
  if ((tid & 63) == 0) { red_s[wave] = lsum; red_c[wave] = lcnt; }
  __syncthreads();
  if (tid == 0) {
    const double s = red_s[0] + red_s[1] + red_s[2] + red_s[3];
    const double c = (double)(red_c[0] + red_c[1] + red_c[2] + red_c[3]);
    const int bid = (blockIdx.z * GY + blockIdx.y) * GX + blockIdx.x;
    partials[bid] = make_double2(s, c);
  }
}

extern "C" __global__ __launch_bounds__(1024)
void boundary_loss_final(const double2* __restrict__ partials,
                         float* __restrict__ out)
{
  __shared__ double red_s[16];
  __shared__ double red_c[16];
  const int tid = threadIdx.x;
  double s = 0.0, c = 0.0;
  for (int i = tid; i < NBLK; i += 1024) {
    const double2 p = partials[i];
    s += p.x;
    c += p.y;
  }
#pragma unroll
  for (int off = 32; off > 0; off >>= 1) {
    s += __shfl_down(s, off, 64);
    c += __shfl_down(c, off, 64);
  }
  const int wave = tid >> 6;
  if ((tid & 63) == 0) { red_s[wave] = s; red_c[wave] = c; }
  __syncthreads();
  if (tid == 0) {
    double ts = 0.0, tc = 0.0;
#pragma unroll
    for (int i = 0; i < 16; ++i) { ts += red_s[i]; tc += red_c[i]; }
    if (tc < 1.0) tc = 1.0;
    out[0] = (float)(-ts / tc);
  }
}

extern "C" void kernel_launch(void* const* d_in, const int* in_sizes, int n_in,
                              void* d_out, int out_size, void* d_ws, size_t ws_size,
                              hipStream_t stream)
{
  const float* logits = (const float*)d_in[0];
  const int* labels = (const int*)d_in[1];
  float* out = (float*)d_out;
  double2* partials = (double2*)d_ws;  // NBLK*16 B = 107,520 B; every slot
                                       // written by main -> no init needed.

  dim3 grid(GX, GY, B_);
  boundary_loss_main<<<grid, 256, 0, stream>>>(logits, labels, partials);
  boundary_loss_final<<<1, 1024, 0, stream>>>(partials, out);
}